// Round 5
// baseline (505.665 us; speedup 1.0000x reference)
//
#include <hip/hip_runtime.h>
#include <math.h>

#define N_NODES  100000
#define N_EDGES  1600000
#define N_GRAPHS 1000
#define F_IN     9
#define HID      64
#define NB_SCAN  391   // ceil(N_NODES / 256)
#define NBUCK    98    // ceil(N_NODES / 1024), bucket = dst >> 10
#define CHUNK    4096  // edges per bscatter block

typedef unsigned int  uint32;
typedef unsigned short ushort16;

// ---------------------------------------------------------------------------
// Workspace layout (4-byte words):
//   [0,       100000)    deg     (int)   -- zeroed
//   [100000,  200000)    cursor  (int)   -- zeroed
//   [200000,  264000)    pool    (float) -- zeroed  (N_GRAPHS*64)
//   [264000,  264098)    bcnt    (int)   -- zeroed  (bucket counts)
//   [264104,  264202)    gcur    (int)   -- zeroed  (bucket cursors)
//   ZERO region = [0, 264208)
//   [264208,  364209)    rowptr  (int, N+1)
//   [364212,  1964212)   col     (int, E)
//   [1964212, 8364212)   h1      (float, N*64)
//     ebuf (int2, E = 3.2M words) aliases h1: consumed by fill2 before
//     node_l1 writes h1.
//   [8364212, 9164212)   x16b    (bf16, N*16 = 800K words)
//   [9164212, 10764212)  s16     (float, N*16)
//     y (bf16, N*64 = 3.2M words) occupies [8364212, 11564212), aliasing
//     x16b+s16: both dead before gemm2 writes y.
//   [11564212,11564603)  bsum    (int, NB_SCAN)
// ---------------------------------------------------------------------------

__device__ __forceinline__ float bfl(uint32 w) { return __uint_as_float(w << 16); }
__device__ __forceinline__ float bfh(uint32 w) { return __uint_as_float(w & 0xffff0000u); }
__device__ __forceinline__ ushort16 f2bf(float f) {
    uint32 u = __float_as_uint(f);
    u += 0x7fffu + ((u >> 16) & 1u);           // round-to-nearest-even
    return (ushort16)(u >> 16);
}

// degree histogram + bucket histogram
__global__ void hist_kernel(const int* __restrict__ ei,
                            int* __restrict__ deg,
                            int* __restrict__ bcnt) {
    __shared__ int lb[NBUCK];
    int tid = threadIdx.x;
    for (int i = tid; i < NBUCK; i += 256) lb[i] = 0;
    __syncthreads();
    int e = blockIdx.x * 256 + tid;
    if (e < N_EDGES) {
        int dst = ei[N_EDGES + e];
        atomicAdd(&deg[dst], 1);
        atomicAdd(&lb[dst >> 10], 1);
    }
    __syncthreads();
    for (int i = tid; i < NBUCK; i += 256)
        if (lb[i]) atomicAdd(&bcnt[i], lb[i]);
}

// scan phase 1: per-block (256 elems) sums of deg
__global__ void scan1_kernel(const int* __restrict__ deg, int* __restrict__ bsum) {
    int i = blockIdx.x * 256 + threadIdx.x;
    int v = (i < N_NODES) ? deg[i] : 0;
    #pragma unroll
    for (int off = 1; off < 64; off <<= 1) v += __shfl_xor(v, off, 64);
    __shared__ int ws[4];
    if ((threadIdx.x & 63) == 0) ws[threadIdx.x >> 6] = v;
    __syncthreads();
    if (threadIdx.x == 0) bsum[blockIdx.x] = ws[0] + ws[1] + ws[2] + ws[3];
}

// scan phase 2: block 0 scans bsum[NB_SCAN]; block 1 scans bcnt -> gcur
__global__ void scan2_kernel(int* __restrict__ bsum,
                             const int* __restrict__ bcnt,
                             int* __restrict__ gcur) {
    __shared__ int ts[512];
    int t = threadIdx.x;
    if (blockIdx.x == 0) {
        ts[t] = (t < NB_SCAN) ? bsum[t] : 0;
        __syncthreads();
        for (int off = 1; off < 512; off <<= 1) {
            int v = (t >= off) ? ts[t - off] : 0;
            __syncthreads();
            ts[t] += v;
            __syncthreads();
        }
        if (t < NB_SCAN) bsum[t] = (t == 0) ? 0 : ts[t - 1];
    } else {
        ts[t] = (t < NBUCK) ? bcnt[t] : 0;
        __syncthreads();
        for (int off = 1; off < 512; off <<= 1) {
            int v = (t >= off) ? ts[t - off] : 0;
            __syncthreads();
            ts[t] += v;
            __syncthreads();
        }
        if (t < NBUCK) gcur[t] = (t == 0) ? 0 : ts[t - 1];
    }
}

// scan phase 3: in-block exclusive scan + block offset -> rowptr
__global__ void scan3_kernel(const int* __restrict__ deg,
                             const int* __restrict__ bsum,
                             int* __restrict__ rowptr) {
    int i = blockIdx.x * 256 + threadIdx.x;
    int v = (i < N_NODES) ? deg[i] : 0;
    int lane = threadIdx.x & 63;
    int wid = threadIdx.x >> 6;
    int s = v;
    #pragma unroll
    for (int off = 1; off < 64; off <<= 1) {
        int u = __shfl_up(s, off, 64);
        if (lane >= off) s += u;
    }
    __shared__ int wsum[4];
    if (lane == 63) wsum[wid] = s;
    __syncthreads();
    int add = 0;
    for (int w = 0; w < wid; ++w) add += wsum[w];
    if (i < N_NODES) rowptr[i] = s - v + add + bsum[blockIdx.x];
    if (blockIdx.x == 0 && threadIdx.x == 0) rowptr[N_NODES] = N_EDGES;
}

// bucket-partition edges into ebuf (block-aggregated reservation)
__global__ __launch_bounds__(256) void bscatter_kernel(const int* __restrict__ ei,
                                                       int* __restrict__ gcur,
                                                       int2* __restrict__ ebuf) {
    __shared__ int lcnt[NBUCK], lbase[NBUCK];
    int tid = threadIdx.x;
    int e0 = blockIdx.x * CHUNK;
    int e1 = e0 + CHUNK; if (e1 > N_EDGES) e1 = N_EDGES;
    for (int i = tid; i < NBUCK; i += 256) lcnt[i] = 0;
    __syncthreads();
    for (int e = e0 + tid; e < e1; e += 256)
        atomicAdd(&lcnt[ei[N_EDGES + e] >> 10], 1);
    __syncthreads();
    for (int i = tid; i < NBUCK; i += 256)
        lbase[i] = atomicAdd(&gcur[i], lcnt[i]);
    __syncthreads();
    for (int i = tid; i < NBUCK; i += 256) lcnt[i] = 0;
    __syncthreads();
    for (int e = e0 + tid; e < e1; e += 256) {
        int src = ei[e];
        int dst = ei[N_EDGES + e];
        int b = dst >> 10;
        int pos = lbase[b] + atomicAdd(&lcnt[b], 1);
        ebuf[pos] = make_int2(src, dst);
    }
}

// CSR fill from bucket-sorted ebuf; XCD-swizzled so each bucket stays on one XCD
__global__ void fill2_kernel(const int2* __restrict__ ebuf,
                             const int* __restrict__ rowptr,
                             int* __restrict__ cursor,
                             int* __restrict__ col) {
    int nwg = gridDim.x;
    int q = nwg >> 3, r = nwg & 7;
    int xcd = blockIdx.x & 7, off = blockIdx.x >> 3;
    int bid = (xcd < r ? xcd * (q + 1) : r * (q + 1) + (xcd - r) * q) + off;
    int e = bid * 256 + threadIdx.x;
    if (e >= N_EDGES) return;
    int2 sd = ebuf[e];
    int pos = atomicAdd(&cursor[sd.y], 1);
    col[rowptr[sd.y] + pos] = sd.x;
}

// pad x [N,9] -> x16b [N,16] bf16 (zeros in cols 9..15); one thread per node
__global__ void pad_x_kernel(const float* __restrict__ x, ushort16* __restrict__ x16b) {
    int n = blockIdx.x * 256 + threadIdx.x;
    if (n >= N_NODES) return;
    uint32 w[8];
    #pragma unroll
    for (int p = 0; p < 8; ++p) {
        int k0 = p * 2, k1 = p * 2 + 1;
        uint32 lo = (k0 < F_IN) ? f2bf(x[n * F_IN + k0]) : 0u;
        uint32 hi = (k1 < F_IN) ? f2bf(x[n * F_IN + k1]) : 0u;
        w[p] = lo | (hi << 16);
    }
    uint4* dst = reinterpret_cast<uint4*>(&x16b[(size_t)n * 16]);
    dst[0] = make_uint4(w[0], w[1], w[2], w[3]);
    dst[1] = make_uint4(w[4], w[5], w[6], w[7]);
}

// layer-1 gather on bf16 x16b: 4 threads per node, 4 features (uint2) each
__global__ void agg1_kernel(const ushort16* __restrict__ x16b,
                            const int* __restrict__ rowptr,
                            const int* __restrict__ col,
                            float* __restrict__ s16) {
    int t = blockIdx.x * blockDim.x + threadIdx.x;
    if (t >= N_NODES * 4) return;
    int n = t >> 2, q4 = (t & 3) * 4;
    int lo = rowptr[n], hi = rowptr[n + 1];
    float4 a = make_float4(0.f, 0.f, 0.f, 0.f);
    #pragma unroll 4
    for (int i = lo; i < hi; ++i) {
        int c = col[i];
        uint2 d = *reinterpret_cast<const uint2*>(&x16b[(size_t)c * 16 + q4]);
        a.x += bfl(d.x); a.y += bfh(d.x);
        a.z += bfl(d.y); a.w += bfh(d.y);
    }
    *reinterpret_cast<float4*>(&s16[(size_t)n * 16 + q4]) = a;
}

// layer-1 dense: thread per (node, out-feature)
__global__ void node_l1_kernel(const float* __restrict__ x,
                               const float* __restrict__ s16,
                               const int* __restrict__ rowptr,
                               const float* __restrict__ Wl1,
                               const float* __restrict__ Wr1,
                               const float* __restrict__ b1,
                               float* __restrict__ h1) {
    int t = blockIdx.x * blockDim.x + threadIdx.x;
    if (t >= N_NODES * HID) return;
    int n = t >> 6;
    int j = t & 63;
    float inv = 1.0f / fmaxf((float)(rowptr[n + 1] - rowptr[n]), 1.0f);
    float acc = b1[j];
    #pragma unroll
    for (int k = 0; k < F_IN; ++k) {
        acc += s16[n * 16 + k] * inv * Wl1[k * HID + j];
        acc += x[n * F_IN + k] * Wr1[k * HID + j];
    }
    h1[t] = fmaxf(acc, 0.0f);
}

// register-tiled GEMM: y(bf16) = h1 @ Wl2 ; z = h1 @ Wr2 + b2 -> pool atomics
__global__ __launch_bounds__(256) void gemm2_kernel(const float* __restrict__ h1,
                                                    const float* __restrict__ Wl2,
                                                    const float* __restrict__ Wr2,
                                                    const float* __restrict__ b2,
                                                    const int* __restrict__ batch,
                                                    ushort16* __restrict__ yb,
                                                    float* __restrict__ pool) {
    __shared__ float wsw[HID * 128];     // combined [k][ Wl2 | Wr2 ]
    __shared__ float hs[64 * 65];        // 64 nodes x 64 k, +1 pad
    int tid = threadIdx.x;
    int n0 = blockIdx.x * 64;
    for (int i = tid; i < HID * HID; i += 256) {
        int k = i >> 6, j = i & 63;
        wsw[k * 128 + j]      = Wl2[i];
        wsw[k * 128 + 64 + j] = Wr2[i];
    }
    for (int i = tid; i < 64 * HID; i += 256) {
        int r = i >> 6, k = i & 63;
        int n = n0 + r;
        hs[r * 65 + k] = (n < N_NODES) ? h1[(size_t)n * HID + k] : 0.0f;
    }
    __syncthreads();

    int tm = tid >> 4, tn = tid & 15;
    int r0 = tm * 4, c0 = tn * 8;
    float acc[4][8];
    #pragma unroll
    for (int r = 0; r < 4; ++r)
        #pragma unroll
        for (int c = 0; c < 8; ++c) acc[r][c] = 0.0f;

    #pragma unroll 4
    for (int k = 0; k < HID; ++k) {
        float a0 = hs[(r0 + 0) * 65 + k];
        float a1 = hs[(r0 + 1) * 65 + k];
        float a2 = hs[(r0 + 2) * 65 + k];
        float a3 = hs[(r0 + 3) * 65 + k];
        const float* wrow = &wsw[k * 128 + c0];
        #pragma unroll
        for (int c = 0; c < 8; ++c) {
            float w = wrow[c];
            acc[0][c] += a0 * w;
            acc[1][c] += a1 * w;
            acc[2][c] += a2 * w;
            acc[3][c] += a3 * w;
        }
    }

    if (tn < 8) {                        // y half: pack 8 bf16 -> uint4 store
        #pragma unroll
        for (int r = 0; r < 4; ++r) {
            int n = n0 + r0 + r;
            if (n < N_NODES) {
                uint32 w0 = (uint32)f2bf(acc[r][0]) | ((uint32)f2bf(acc[r][1]) << 16);
                uint32 w1 = (uint32)f2bf(acc[r][2]) | ((uint32)f2bf(acc[r][3]) << 16);
                uint32 w2 = (uint32)f2bf(acc[r][4]) | ((uint32)f2bf(acc[r][5]) << 16);
                uint32 w3 = (uint32)f2bf(acc[r][6]) | ((uint32)f2bf(acc[r][7]) << 16);
                *reinterpret_cast<uint4*>(&yb[(size_t)n * HID + c0]) =
                    make_uint4(w0, w1, w2, w3);
            }
        }
    }
    __syncthreads();
    if (tn >= 8) {                       // z half -> stage into hs
        int zc = c0 - 64;
        #pragma unroll
        for (int r = 0; r < 4; ++r) {
            int n = n0 + r0 + r;
            bool ok = (n < N_NODES);
            #pragma unroll
            for (int c = 0; c < 8; ++c)
                hs[(r0 + r) * 65 + zc + c] = ok ? (acc[r][c] + b2[zc + c]) : 0.0f;
        }
    }
    __syncthreads();
    if (tid < HID) {                     // grouped pool atomics (batch sorted)
        int j = tid;
        int cur = batch[(n0 < N_NODES) ? n0 : (N_NODES - 1)];
        float v = hs[0 * 65 + j];
        for (int r = 1; r < 64; ++r) {
            int n = n0 + r;
            int g = batch[(n < N_NODES) ? n : (N_NODES - 1)];
            float val = hs[r * 65 + j];
            if (g == cur) v += val;
            else { atomicAdd(&pool[cur * HID + j], v); cur = g; v = val; }
        }
        atomicAdd(&pool[cur * HID + j], v);
    }
}

// layer-2 gather on bf16 y: wave per node; lanes = 4 edge-slots x 16 groups
__global__ __launch_bounds__(1024) void gather2_kernel(const ushort16* __restrict__ yb,
                                                       const int* __restrict__ rowptr,
                                                       const int* __restrict__ col,
                                                       const int* __restrict__ batch,
                                                       float* __restrict__ pool) {
    __shared__ float sh[16][HID];
    int w = threadIdx.x >> 6;
    int lane = threadIdx.x & 63;
    int q = lane >> 4;
    int f4 = (lane & 15) * 4;
    int n = blockIdx.x * 16 + w;
    int lo = rowptr[n], hi = rowptr[n + 1];
    float4 acc = make_float4(0.f, 0.f, 0.f, 0.f);
    #pragma unroll 2
    for (int i = lo + q; i < hi; i += 4) {
        int c = col[i];
        uint2 d = *reinterpret_cast<const uint2*>(&yb[(size_t)c * HID + f4]);
        acc.x += bfl(d.x); acc.y += bfh(d.x);
        acc.z += bfl(d.y); acc.w += bfh(d.y);
    }
    acc.x += __shfl_xor(acc.x, 16, 64);
    acc.y += __shfl_xor(acc.y, 16, 64);
    acc.z += __shfl_xor(acc.z, 16, 64);
    acc.w += __shfl_xor(acc.w, 16, 64);
    acc.x += __shfl_xor(acc.x, 32, 64);
    acc.y += __shfl_xor(acc.y, 32, 64);
    acc.z += __shfl_xor(acc.z, 32, 64);
    acc.w += __shfl_xor(acc.w, 32, 64);
    float inv = 1.0f / fmaxf((float)(hi - lo), 1.0f);
    if (lane < 16) {
        float4 r = make_float4(acc.x * inv, acc.y * inv, acc.z * inv, acc.w * inv);
        *reinterpret_cast<float4*>(&sh[w][f4]) = r;
    }
    __syncthreads();
    if (threadIdx.x < HID) {
        int j = threadIdx.x;
        int base = blockIdx.x * 16;
        int cur = batch[base];
        float v = sh[0][j];
        for (int r = 1; r < 16; ++r) {
            int g = batch[base + r];
            float val = sh[r][j];
            if (g == cur) v += val;
            else { atomicAdd(&pool[cur * HID + j], v); cur = g; v = val; }
        }
        atomicAdd(&pool[cur * HID + j], v);
    }
}

// readout: one wave per graph; node count via binary search on batch
__global__ void mlp_kernel(const float* __restrict__ pool,
                           const int* __restrict__ batch,
                           const float* __restrict__ Wm1,
                           const float* __restrict__ bm1,
                           const float* __restrict__ Wm2,
                           const float* __restrict__ bm2,
                           float* __restrict__ out) {
    __shared__ float sx[4][HID];
    int t = blockIdx.x * blockDim.x + threadIdx.x;
    int g = t >> 6;
    int j = t & 63;
    int w = threadIdx.x >> 6;
    if (g >= N_GRAPHS) return;
    int lo = 0, hi = N_NODES;
    while (lo < hi) { int m = (lo + hi) >> 1; if (batch[m] < g) lo = m + 1; else hi = m; }
    int start = lo;
    lo = 0; hi = N_NODES;
    while (lo < hi) { int m = (lo + hi) >> 1; if (batch[m] < g + 1) lo = m + 1; else hi = m; }
    int cntg = lo - start;
    float inv = 1.0f / fmaxf((float)cntg, 1.0f);
    sx[w][j] = pool[g * HID + j] * inv;
    if (j < 32) {
        float a = bm1[j];
        #pragma unroll 8
        for (int k = 0; k < HID; ++k)
            a += sx[w][k] * Wm1[k * 32 + j];
        float r = fmaxf(a, 0.0f) * Wm2[j];
        #pragma unroll
        for (int off = 16; off > 0; off >>= 1)
            r += __shfl_down(r, off, 32);
        if (j == 0)
            out[g] = 1.0f / (1.0f + expf(-(r + bm2[0])));
    }
}

extern "C" void kernel_launch(void* const* d_in, const int* in_sizes, int n_in,
                              void* d_out, int out_size, void* d_ws, size_t ws_size,
                              hipStream_t stream) {
    const float* x    = (const float*)d_in[0];
    const int*   ei   = (const int*)d_in[1];
    // d_in[2] = edge_attr (all zeros, unused)
    const int*   batch= (const int*)d_in[3];
    const float* Wl1  = (const float*)d_in[4];
    const float* Wr1  = (const float*)d_in[5];
    const float* b1   = (const float*)d_in[6];
    const float* Wl2  = (const float*)d_in[7];
    const float* Wr2  = (const float*)d_in[8];
    const float* b2   = (const float*)d_in[9];
    const float* Wm1  = (const float*)d_in[10];
    const float* bm1  = (const float*)d_in[11];
    const float* Wm2  = (const float*)d_in[12];
    const float* bm2  = (const float*)d_in[13];
    float* out = (float*)d_out;

    int*   wsi    = (int*)d_ws;
    float* wsf    = (float*)d_ws;
    int*      deg    = wsi;
    int*      cursor = wsi + 100000;
    float*    pool   = wsf + 200000;
    int*      bcnt   = wsi + 264000;
    int*      gcur   = wsi + 264104;
    int*      rowptr = wsi + 264208;
    int*      col    = wsi + 364212;
    float*    h1     = wsf + 1964212;
    int2*     ebuf   = (int2*)(wsi + 1964212);           // aliases h1
    ushort16* x16b   = (ushort16*)(wsi + 8364212);
    float*    s16    = wsf + 9164212;
    ushort16* yb     = (ushort16*)(wsi + 8364212);       // aliases x16b+s16
    int*      bsum   = wsi + 11564212;

    hipMemsetAsync(d_ws, 0, 264208 * sizeof(int), stream);

    {   int th = 256, bl = (N_EDGES + th - 1) / th;
        hist_kernel<<<bl, th, 0, stream>>>(ei, deg, bcnt);
    }
    scan1_kernel<<<NB_SCAN, 256, 0, stream>>>(deg, bsum);
    scan2_kernel<<<2, 512, 0, stream>>>(bsum, bcnt, gcur);
    scan3_kernel<<<NB_SCAN, 256, 0, stream>>>(deg, bsum, rowptr);
    {   int bl = (N_EDGES + CHUNK - 1) / CHUNK;          // 391
        bscatter_kernel<<<bl, 256, 0, stream>>>(ei, gcur, ebuf);
    }
    {   int th = 256, bl = N_EDGES / th;                 // 6250
        fill2_kernel<<<bl, th, 0, stream>>>(ebuf, rowptr, cursor, col);
    }
    {   int th = 256, bl = (N_NODES + th - 1) / th;
        pad_x_kernel<<<bl, th, 0, stream>>>(x, x16b);
    }
    {   int th = 256, bl = (N_NODES * 4 + th - 1) / th;
        agg1_kernel<<<bl, th, 0, stream>>>(x16b, rowptr, col, s16);
    }
    {   int th = 256, bl = (N_NODES * HID) / th;
        node_l1_kernel<<<bl, th, 0, stream>>>(x, s16, rowptr, Wl1, Wr1, b1, h1);
    }
    {   int th = 256, bl = (N_NODES + 63) / 64;
        gemm2_kernel<<<bl, th, 0, stream>>>(h1, Wl2, Wr2, b2, batch, yb, pool);
    }
    {   int th = 1024, bl = N_NODES / 16;
        gather2_kernel<<<bl, th, 0, stream>>>(yb, rowptr, col, batch, pool);
    }
    {   int th = 256, bl = (N_GRAPHS * 64) / th;
        mlp_kernel<<<bl, th, 0, stream>>>(pool, batch, Wm1, bm1, Wm2, bm2, out);
    }
}

// Round 6
// 237.432 us; speedup vs baseline: 2.1297x; 2.1297x over previous
//
#include <hip/hip_runtime.h>
#include <math.h>

#define N_NODES  100000
#define N_EDGES  1600000
#define N_GRAPHS 1000
#define F_IN     9
#define HID      64
#define NBUCK    98    // ceil(N_NODES / 1024), bucket = dst >> 10
#define CHUNK    4096  // edges per bhist/bscatter block

typedef unsigned int   uint32;
typedef unsigned short ushort16;

// ---------------------------------------------------------------------------
// Workspace layout (4-byte words):
//   [0,       64000)    pool    (float) -- zeroed  (N_GRAPHS*64)
//   [64000,   64098)    bcnt    (int)   -- zeroed  (bucket counts)
//   [64100,   64198)    gcur    (int)   -- (re)written by scan_b
//   [64200,   64299)    gbase   (int, NBUCK+1)
//   [64304,   164305)   rowptr  (int, N+1)
//   [164308,  1764308)  col     (int, E)
//   [1764308, 4964308)  ebuf    (int2, E)
//   [4964308, 5764308)  x16b    (bf16, N*16)
//   [5764308, 7364308)  s16     (float, N*16)  -- pre-scaled by 1/deg
//   [7364308, 10564308) yb      (bf16, N*64)
// ZERO region = [0, 64200). Total 10.56M words = 42.3 MB.
// ---------------------------------------------------------------------------

__device__ __forceinline__ float bfl(uint32 w) { return __uint_as_float(w << 16); }
__device__ __forceinline__ float bfh(uint32 w) { return __uint_as_float(w & 0xffff0000u); }
__device__ __forceinline__ ushort16 f2bf(float f) {
    uint32 u = __float_as_uint(f);
    u += 0x7fffu + ((u >> 16) & 1u);           // round-to-nearest-even
    return (ushort16)(u >> 16);
}

// bucket histogram only: LDS count per block, 98*391 flush atomics total
__global__ void bhist_kernel(const int* __restrict__ ei, int* __restrict__ bcnt) {
    __shared__ int lb[NBUCK];
    int tid = threadIdx.x;
    for (int i = tid; i < NBUCK; i += 256) lb[i] = 0;
    __syncthreads();
    int e0 = blockIdx.x * CHUNK;
    int e1 = e0 + CHUNK; if (e1 > N_EDGES) e1 = N_EDGES;
    for (int e = e0 + tid; e < e1; e += 256)
        atomicAdd(&lb[ei[N_EDGES + e] >> 10], 1);
    __syncthreads();
    for (int i = tid; i < NBUCK; i += 256)
        if (lb[i]) atomicAdd(&bcnt[i], lb[i]);
}

// exclusive scan of bcnt[98] -> gbase (and gcur working copy); gbase[98]=E
__global__ void scan_b_kernel(const int* __restrict__ bcnt,
                              int* __restrict__ gbase,
                              int* __restrict__ gcur) {
    int t = threadIdx.x;                 // 128 threads, 2 waves
    int v = (t < NBUCK) ? bcnt[t] : 0;
    int lane = t & 63;
    int s = v;
    #pragma unroll
    for (int off = 1; off < 64; off <<= 1) {
        int u = __shfl_up(s, off, 64);
        if (lane >= off) s += u;
    }
    __shared__ int w0sum;
    if (t == 63) w0sum = s;
    __syncthreads();
    if (t >= 64) s += w0sum;
    if (t < NBUCK) { gbase[t] = s - v; gcur[t] = s - v; }
    if (t == NBUCK - 1) gbase[NBUCK] = s;
}

// bucket-partition edges into ebuf (block-aggregated reservation)
__global__ __launch_bounds__(256) void bscatter_kernel(const int* __restrict__ ei,
                                                       int* __restrict__ gcur,
                                                       int2* __restrict__ ebuf) {
    __shared__ int lcnt[NBUCK], lbase[NBUCK];
    int tid = threadIdx.x;
    int e0 = blockIdx.x * CHUNK;
    int e1 = e0 + CHUNK; if (e1 > N_EDGES) e1 = N_EDGES;
    for (int i = tid; i < NBUCK; i += 256) lcnt[i] = 0;
    __syncthreads();
    for (int e = e0 + tid; e < e1; e += 256)
        atomicAdd(&lcnt[ei[N_EDGES + e] >> 10], 1);
    __syncthreads();
    for (int i = tid; i < NBUCK; i += 256)
        lbase[i] = atomicAdd(&gcur[i], lcnt[i]);
    __syncthreads();
    for (int i = tid; i < NBUCK; i += 256) lcnt[i] = 0;
    __syncthreads();
    for (int e = e0 + tid; e < e1; e += 256) {
        int src = ei[e];
        int dst = ei[N_EDGES + e];
        int b = dst >> 10;
        int pos = lbase[b] + atomicAdd(&lcnt[b], 1);
        ebuf[pos] = make_int2(src, dst);
    }
}

// per-bucket CSR build: LDS node-count + scan + place; zero global atomics
__global__ __launch_bounds__(1024) void build_csr_kernel(const int2* __restrict__ ebuf,
                                                         const int* __restrict__ gbase,
                                                         int* __restrict__ rowptr,
                                                         int* __restrict__ col) {
    __shared__ int cnt[1024];
    __shared__ int cur[1024];
    __shared__ int wsum[16];
    int b = blockIdx.x;
    int n0 = b << 10;
    int e0 = gbase[b], e1 = gbase[b + 1];
    int tid = threadIdx.x;
    cnt[tid] = 0;
    __syncthreads();
    for (int e = e0 + tid; e < e1; e += 1024)
        atomicAdd(&cnt[ebuf[e].y - n0], 1);
    __syncthreads();
    int v = cnt[tid];
    int lane = tid & 63, wid = tid >> 6;
    int s = v;
    #pragma unroll
    for (int off = 1; off < 64; off <<= 1) {
        int u = __shfl_up(s, off, 64);
        if (lane >= off) s += u;
    }
    if (lane == 63) wsum[wid] = s;
    __syncthreads();
    int add = 0;
    for (int w = 0; w < wid; ++w) add += wsum[w];
    int off_ex = s - v + add;            // exclusive scan, relative to e0
    int n = n0 + tid;
    if (n < N_NODES) rowptr[n] = e0 + off_ex;
    cur[tid] = off_ex;
    __syncthreads();
    for (int e = e0 + tid; e < e1; e += 1024) {
        int2 sd = ebuf[e];
        int pos = atomicAdd(&cur[sd.y - n0], 1);
        col[e0 + pos] = sd.x;
    }
    if (b == 0 && tid == 0) rowptr[N_NODES] = N_EDGES;
}

// pad x [N,9] -> x16b [N,16] bf16 (zeros in cols 9..15); one thread per node
__global__ void pad_x_kernel(const float* __restrict__ x, ushort16* __restrict__ x16b) {
    int n = blockIdx.x * 256 + threadIdx.x;
    if (n >= N_NODES) return;
    uint32 w[8];
    #pragma unroll
    for (int p = 0; p < 8; ++p) {
        int k0 = p * 2, k1 = p * 2 + 1;
        uint32 lo = (k0 < F_IN) ? f2bf(x[n * F_IN + k0]) : 0u;
        uint32 hi = (k1 < F_IN) ? f2bf(x[n * F_IN + k1]) : 0u;
        w[p] = lo | (hi << 16);
    }
    uint4* dst = reinterpret_cast<uint4*>(&x16b[(size_t)n * 16]);
    dst[0] = make_uint4(w[0], w[1], w[2], w[3]);
    dst[1] = make_uint4(w[4], w[5], w[6], w[7]);
}

// layer-1 gather on bf16 x16b, pre-scaled by 1/deg: 4 threads/node, 4 feats each
__global__ void agg1_kernel(const ushort16* __restrict__ x16b,
                            const int* __restrict__ rowptr,
                            const int* __restrict__ col,
                            float* __restrict__ s16) {
    int t = blockIdx.x * blockDim.x + threadIdx.x;
    if (t >= N_NODES * 4) return;
    int n = t >> 2, q4 = (t & 3) * 4;
    int lo = rowptr[n], hi = rowptr[n + 1];
    float4 a = make_float4(0.f, 0.f, 0.f, 0.f);
    #pragma unroll 4
    for (int i = lo; i < hi; ++i) {
        int c = col[i];
        uint2 d = *reinterpret_cast<const uint2*>(&x16b[(size_t)c * 16 + q4]);
        a.x += bfl(d.x); a.y += bfh(d.x);
        a.z += bfl(d.y); a.w += bfh(d.y);
    }
    float inv = 1.0f / fmaxf((float)(hi - lo), 1.0f);
    a.x *= inv; a.y *= inv; a.z *= inv; a.w *= inv;
    *reinterpret_cast<float4*>(&s16[(size_t)n * 16 + q4]) = a;
}

// fused: layer-1 dense (in LDS) + layer-2 GEMM + pool atomics.
// tile = 64 nodes; y(bf16) = h1 @ Wl2 ; z = h1 @ Wr2 + b2 -> pool.
__global__ __launch_bounds__(256) void gemm2_kernel(const float* __restrict__ x,
                                                    const float* __restrict__ s16,
                                                    const float* __restrict__ Wl1,
                                                    const float* __restrict__ Wr1,
                                                    const float* __restrict__ b1,
                                                    const float* __restrict__ Wl2,
                                                    const float* __restrict__ Wr2,
                                                    const float* __restrict__ b2,
                                                    const int* __restrict__ batch,
                                                    ushort16* __restrict__ yb,
                                                    float* __restrict__ pool) {
    __shared__ float wsw[HID * 128];     // [k][ Wl2 | Wr2 ]
    __shared__ float hs[64 * 65];        // h1 tile, +1 pad
    __shared__ float w1s[F_IN * 128];    // [f][ Wl1 | Wr1 ]
    __shared__ float ss[64 * 17];        // s16 tile (pre-scaled agg)
    __shared__ float xs[64 * 10];        // x tile (f32, exact)
    int tid = threadIdx.x;
    int n0 = blockIdx.x * 64;
    for (int i = tid; i < HID * HID; i += 256) {
        int k = i >> 6, j = i & 63;
        wsw[k * 128 + j]      = Wl2[i];
        wsw[k * 128 + 64 + j] = Wr2[i];
    }
    for (int i = tid; i < F_IN * HID; i += 256) {
        int f = i >> 6, j = i & 63;
        w1s[f * 128 + j]      = Wl1[i];
        w1s[f * 128 + 64 + j] = Wr1[i];
    }
    for (int i = tid; i < 64 * 16; i += 256) {
        int r = i >> 4, f = i & 15;
        int n = n0 + r;
        ss[r * 17 + f] = (n < N_NODES) ? s16[(size_t)n * 16 + f] : 0.0f;
    }
    for (int i = tid; i < 64 * F_IN; i += 256) {
        int r = i / F_IN, f = i - r * F_IN;
        int n = n0 + r;
        xs[r * 10 + f] = (n < N_NODES) ? x[(size_t)n * F_IN + f] : 0.0f;
    }
    __syncthreads();

    // layer-1 dense: hs[r][k] = relu(b1[k] + agg.Wl1 + x.Wr1)
    for (int i = tid; i < 64 * HID; i += 256) {
        int r = i >> 6, k = i & 63;
        float v = b1[k];
        #pragma unroll
        for (int f = 0; f < F_IN; ++f)
            v += ss[r * 17 + f] * w1s[f * 128 + k]
               + xs[r * 10 + f] * w1s[f * 128 + 64 + k];
        hs[r * 65 + k] = fmaxf(v, 0.0f);
    }
    __syncthreads();

    int tm = tid >> 4, tn = tid & 15;
    int r0 = tm * 4, c0 = tn * 8;
    float acc[4][8];
    #pragma unroll
    for (int r = 0; r < 4; ++r)
        #pragma unroll
        for (int c = 0; c < 8; ++c) acc[r][c] = 0.0f;

    #pragma unroll 4
    for (int k = 0; k < HID; ++k) {
        float a0 = hs[(r0 + 0) * 65 + k];
        float a1 = hs[(r0 + 1) * 65 + k];
        float a2 = hs[(r0 + 2) * 65 + k];
        float a3 = hs[(r0 + 3) * 65 + k];
        const float* wrow = &wsw[k * 128 + c0];
        #pragma unroll
        for (int c = 0; c < 8; ++c) {
            float w = wrow[c];
            acc[0][c] += a0 * w;
            acc[1][c] += a1 * w;
            acc[2][c] += a2 * w;
            acc[3][c] += a3 * w;
        }
    }

    if (tn < 8) {                        // y half: pack 8 bf16 -> uint4 store
        #pragma unroll
        for (int r = 0; r < 4; ++r) {
            int n = n0 + r0 + r;
            if (n < N_NODES) {
                uint32 w0 = (uint32)f2bf(acc[r][0]) | ((uint32)f2bf(acc[r][1]) << 16);
                uint32 w1 = (uint32)f2bf(acc[r][2]) | ((uint32)f2bf(acc[r][3]) << 16);
                uint32 w2 = (uint32)f2bf(acc[r][4]) | ((uint32)f2bf(acc[r][5]) << 16);
                uint32 w3 = (uint32)f2bf(acc[r][6]) | ((uint32)f2bf(acc[r][7]) << 16);
                *reinterpret_cast<uint4*>(&yb[(size_t)n * HID + c0]) =
                    make_uint4(w0, w1, w2, w3);
            }
        }
    }
    __syncthreads();
    if (tn >= 8) {                       // z half -> stage into hs
        int zc = c0 - 64;
        #pragma unroll
        for (int r = 0; r < 4; ++r) {
            int n = n0 + r0 + r;
            bool ok = (n < N_NODES);
            #pragma unroll
            for (int c = 0; c < 8; ++c)
                hs[(r0 + r) * 65 + zc + c] = ok ? (acc[r][c] + b2[zc + c]) : 0.0f;
        }
    }
    __syncthreads();
    if (tid < HID) {                     // grouped pool atomics (batch sorted)
        int j = tid;
        int cur = batch[(n0 < N_NODES) ? n0 : (N_NODES - 1)];
        float v = hs[0 * 65 + j];
        for (int r = 1; r < 64; ++r) {
            int n = n0 + r;
            int g = batch[(n < N_NODES) ? n : (N_NODES - 1)];
            float val = hs[r * 65 + j];
            if (g == cur) v += val;
            else { atomicAdd(&pool[cur * HID + j], v); cur = g; v = val; }
        }
        atomicAdd(&pool[cur * HID + j], v);
    }
}

// layer-2 gather on bf16 y: wave per node; lanes = 4 edge-slots x 16 groups
__global__ __launch_bounds__(1024) void gather2_kernel(const ushort16* __restrict__ yb,
                                                       const int* __restrict__ rowptr,
                                                       const int* __restrict__ col,
                                                       const int* __restrict__ batch,
                                                       float* __restrict__ pool) {
    __shared__ float sh[16][HID];
    int w = threadIdx.x >> 6;
    int lane = threadIdx.x & 63;
    int q = lane >> 4;
    int f4 = (lane & 15) * 4;
    int n = blockIdx.x * 16 + w;
    int lo = rowptr[n], hi = rowptr[n + 1];
    float4 acc = make_float4(0.f, 0.f, 0.f, 0.f);
    #pragma unroll 2
    for (int i = lo + q; i < hi; i += 4) {
        int c = col[i];
        uint2 d = *reinterpret_cast<const uint2*>(&yb[(size_t)c * HID + f4]);
        acc.x += bfl(d.x); acc.y += bfh(d.x);
        acc.z += bfl(d.y); acc.w += bfh(d.y);
    }
    acc.x += __shfl_xor(acc.x, 16, 64);
    acc.y += __shfl_xor(acc.y, 16, 64);
    acc.z += __shfl_xor(acc.z, 16, 64);
    acc.w += __shfl_xor(acc.w, 16, 64);
    acc.x += __shfl_xor(acc.x, 32, 64);
    acc.y += __shfl_xor(acc.y, 32, 64);
    acc.z += __shfl_xor(acc.z, 32, 64);
    acc.w += __shfl_xor(acc.w, 32, 64);
    float inv = 1.0f / fmaxf((float)(hi - lo), 1.0f);
    if (lane < 16) {
        float4 r = make_float4(acc.x * inv, acc.y * inv, acc.z * inv, acc.w * inv);
        *reinterpret_cast<float4*>(&sh[w][f4]) = r;
    }
    __syncthreads();
    if (threadIdx.x < HID) {
        int j = threadIdx.x;
        int base = blockIdx.x * 16;
        int cur = batch[base];
        float v = sh[0][j];
        for (int r = 1; r < 16; ++r) {
            int g = batch[base + r];
            float val = sh[r][j];
            if (g == cur) v += val;
            else { atomicAdd(&pool[cur * HID + j], v); cur = g; v = val; }
        }
        atomicAdd(&pool[cur * HID + j], v);
    }
}

// readout: one wave per graph; node count via binary search on batch
__global__ void mlp_kernel(const float* __restrict__ pool,
                           const int* __restrict__ batch,
                           const float* __restrict__ Wm1,
                           const float* __restrict__ bm1,
                           const float* __restrict__ Wm2,
                           const float* __restrict__ bm2,
                           float* __restrict__ out) {
    __shared__ float sx[4][HID];
    int t = blockIdx.x * blockDim.x + threadIdx.x;
    int g = t >> 6;
    int j = t & 63;
    int w = threadIdx.x >> 6;
    if (g >= N_GRAPHS) return;
    int lo = 0, hi = N_NODES;
    while (lo < hi) { int m = (lo + hi) >> 1; if (batch[m] < g) lo = m + 1; else hi = m; }
    int start = lo;
    lo = 0; hi = N_NODES;
    while (lo < hi) { int m = (lo + hi) >> 1; if (batch[m] < g + 1) lo = m + 1; else hi = m; }
    int cntg = lo - start;
    float inv = 1.0f / fmaxf((float)cntg, 1.0f);
    sx[w][j] = pool[g * HID + j] * inv;
    if (j < 32) {
        float a = bm1[j];
        #pragma unroll 8
        for (int k = 0; k < HID; ++k)
            a += sx[w][k] * Wm1[k * 32 + j];
        float r = fmaxf(a, 0.0f) * Wm2[j];
        #pragma unroll
        for (int off = 16; off > 0; off >>= 1)
            r += __shfl_down(r, off, 32);
        if (j == 0)
            out[g] = 1.0f / (1.0f + expf(-(r + bm2[0])));
    }
}

extern "C" void kernel_launch(void* const* d_in, const int* in_sizes, int n_in,
                              void* d_out, int out_size, void* d_ws, size_t ws_size,
                              hipStream_t stream) {
    const float* x    = (const float*)d_in[0];
    const int*   ei   = (const int*)d_in[1];
    // d_in[2] = edge_attr (all zeros, unused)
    const int*   batch= (const int*)d_in[3];
    const float* Wl1  = (const float*)d_in[4];
    const float* Wr1  = (const float*)d_in[5];
    const float* b1   = (const float*)d_in[6];
    const float* Wl2  = (const float*)d_in[7];
    const float* Wr2  = (const float*)d_in[8];
    const float* b2   = (const float*)d_in[9];
    const float* Wm1  = (const float*)d_in[10];
    const float* bm1  = (const float*)d_in[11];
    const float* Wm2  = (const float*)d_in[12];
    const float* bm2  = (const float*)d_in[13];
    float* out = (float*)d_out;

    int*   wsi = (int*)d_ws;
    float* wsf = (float*)d_ws;
    float*    pool   = wsf;
    int*      bcnt   = wsi + 64000;
    int*      gcur   = wsi + 64100;
    int*      gbase  = wsi + 64200;
    int*      rowptr = wsi + 64304;
    int*      col    = wsi + 164308;
    int2*     ebuf   = (int2*)(wsi + 1764308);
    ushort16* x16b   = (ushort16*)(wsi + 4964308);
    float*    s16    = wsf + 5764308;
    ushort16* yb     = (ushort16*)(wsi + 7364308);

    hipMemsetAsync(d_ws, 0, 64200 * sizeof(int), stream);   // pool + bcnt

    {   int bl = (N_EDGES + CHUNK - 1) / CHUNK;             // 391
        bhist_kernel<<<bl, 256, 0, stream>>>(ei, bcnt);
    }
    scan_b_kernel<<<1, 128, 0, stream>>>(bcnt, gbase, gcur);
    {   int bl = (N_EDGES + CHUNK - 1) / CHUNK;             // 391
        bscatter_kernel<<<bl, 256, 0, stream>>>(ei, gcur, ebuf);
    }
    build_csr_kernel<<<NBUCK, 1024, 0, stream>>>(ebuf, gbase, rowptr, col);
    {   int th = 256, bl = (N_NODES + th - 1) / th;
        pad_x_kernel<<<bl, th, 0, stream>>>(x, x16b);
    }
    {   int th = 256, bl = (N_NODES * 4 + th - 1) / th;
        agg1_kernel<<<bl, th, 0, stream>>>(x16b, rowptr, col, s16);
    }
    {   int th = 256, bl = (N_NODES + 63) / 64;             // 1563
        gemm2_kernel<<<bl, th, 0, stream>>>(x, s16, Wl1, Wr1, b1,
                                            Wl2, Wr2, b2, batch, yb, pool);
    }
    {   int th = 1024, bl = N_NODES / 16;                   // 6250
        gather2_kernel<<<bl, th, 0, stream>>>(yb, rowptr, col, batch, pool);
    }
    {   int th = 256, bl = (N_GRAPHS * 64) / th;
        mlp_kernel<<<bl, th, 0, stream>>>(pool, batch, Wm1, bm1, Wm2, bm2, out);
    }
}

// Round 7
// 185.583 us; speedup vs baseline: 2.7247x; 1.2794x over previous
//
#include <hip/hip_runtime.h>
#include <math.h>

#define N_NODES  100000
#define N_EDGES  1600000
#define N_GRAPHS 1000
#define F_IN     9
#define HID      64
#define NBUCK    196   // ceil(N_NODES / 512), bucket = dst >> 9
#define CHUNK    4096  // edges per bhist/bscatter block

typedef unsigned int   uint32;
typedef unsigned short ushort16;

// ---------------------------------------------------------------------------
// Workspace layout (4-byte words):
//   [0,       64000)    poolA   (float) -- zeroed  (graph-sum of mean-agg(h1))
//   [64000,   128000)   poolH   (float) -- zeroed  (graph-sum of h1)
//   [128000,  128196)   bcnt    (int)   -- zeroed
//   ZERO region = [0, 128200)
//   [128200,  128396)   gcur    (int, NBUCK)
//   [128400,  128597)   gbase   (int, NBUCK+1)
//   [128600,  228601)   rowptr  (int, N+1)
//   [228604,  1828604)  col     (int, E)
//   [1828604, 5028604)  ebuf    (int2, E)
//   [5028604, 5828604)  x16b    (bf16, N*16)
//   [5828604, 7428604)  s16     (float, N*16)  -- pre-scaled by 1/deg
//   [7428604, 10628604) h1b     (bf16, N*64)
// Total 10.63M words = 42.5 MB.
// ---------------------------------------------------------------------------

__device__ __forceinline__ float bfl(uint32 w) { return __uint_as_float(w << 16); }
__device__ __forceinline__ float bfh(uint32 w) { return __uint_as_float(w & 0xffff0000u); }
__device__ __forceinline__ ushort16 f2bf(float f) {
    uint32 u = __float_as_uint(f);
    u += 0x7fffu + ((u >> 16) & 1u);           // round-to-nearest-even
    return (ushort16)(u >> 16);
}

// bucket histogram: LDS count per block, NBUCK*391 flush atomics total
__global__ void bhist_kernel(const int* __restrict__ ei, int* __restrict__ bcnt) {
    __shared__ int lb[NBUCK];
    int tid = threadIdx.x;
    for (int i = tid; i < NBUCK; i += 256) lb[i] = 0;
    __syncthreads();
    int e0 = blockIdx.x * CHUNK;
    int e1 = e0 + CHUNK; if (e1 > N_EDGES) e1 = N_EDGES;
    for (int e = e0 + tid; e < e1; e += 256)
        atomicAdd(&lb[ei[N_EDGES + e] >> 9], 1);
    __syncthreads();
    for (int i = tid; i < NBUCK; i += 256)
        if (lb[i]) atomicAdd(&bcnt[i], lb[i]);
}

// exclusive scan of bcnt[NBUCK] -> gbase/gcur; gbase[NBUCK] = E
__global__ void scan_b_kernel(const int* __restrict__ bcnt,
                              int* __restrict__ gbase,
                              int* __restrict__ gcur) {
    __shared__ int ts[256];
    int t = threadIdx.x;
    int v = (t < NBUCK) ? bcnt[t] : 0;
    ts[t] = v;
    __syncthreads();
    for (int off = 1; off < 256; off <<= 1) {
        int u = (t >= off) ? ts[t - off] : 0;
        __syncthreads();
        ts[t] += u;
        __syncthreads();
    }
    if (t < NBUCK) { int ex = ts[t] - v; gbase[t] = ex; gcur[t] = ex; }
    if (t == NBUCK - 1) gbase[NBUCK] = ts[t];
}

// bucket-partition edges into ebuf (block-aggregated reservation)
__global__ __launch_bounds__(256) void bscatter_kernel(const int* __restrict__ ei,
                                                       int* __restrict__ gcur,
                                                       int2* __restrict__ ebuf) {
    __shared__ int lcnt[NBUCK], lbase[NBUCK];
    int tid = threadIdx.x;
    int e0 = blockIdx.x * CHUNK;
    int e1 = e0 + CHUNK; if (e1 > N_EDGES) e1 = N_EDGES;
    for (int i = tid; i < NBUCK; i += 256) lcnt[i] = 0;
    __syncthreads();
    for (int e = e0 + tid; e < e1; e += 256)
        atomicAdd(&lcnt[ei[N_EDGES + e] >> 9], 1);
    __syncthreads();
    for (int i = tid; i < NBUCK; i += 256)
        lbase[i] = atomicAdd(&gcur[i], lcnt[i]);
    __syncthreads();
    for (int i = tid; i < NBUCK; i += 256) lcnt[i] = 0;
    __syncthreads();
    for (int e = e0 + tid; e < e1; e += 256) {
        int src = ei[e];
        int dst = ei[N_EDGES + e];
        int b = dst >> 9;
        int pos = lbase[b] + atomicAdd(&lcnt[b], 1);
        ebuf[pos] = make_int2(src, dst);
    }
}

// per-bucket CSR build: 512 nodes/bucket, LDS count + scan + place, no global atomics
__global__ __launch_bounds__(512) void build_csr_kernel(const int2* __restrict__ ebuf,
                                                        const int* __restrict__ gbase,
                                                        int* __restrict__ rowptr,
                                                        int* __restrict__ col) {
    __shared__ int cnt[512];
    __shared__ int cur[512];
    __shared__ int wsum[8];
    int b = blockIdx.x;
    int n0 = b << 9;
    int e0 = gbase[b], e1 = gbase[b + 1];
    int tid = threadIdx.x;
    cnt[tid] = 0;
    __syncthreads();
    for (int e = e0 + tid; e < e1; e += 512)
        atomicAdd(&cnt[ebuf[e].y - n0], 1);
    __syncthreads();
    int v = cnt[tid];
    int lane = tid & 63, wid = tid >> 6;
    int s = v;
    #pragma unroll
    for (int off = 1; off < 64; off <<= 1) {
        int u = __shfl_up(s, off, 64);
        if (lane >= off) s += u;
    }
    if (lane == 63) wsum[wid] = s;
    __syncthreads();
    int add = 0;
    for (int w = 0; w < wid; ++w) add += wsum[w];
    int off_ex = s - v + add;            // exclusive scan, relative to e0
    int n = n0 + tid;
    if (n < N_NODES) rowptr[n] = e0 + off_ex;
    cur[tid] = off_ex;
    __syncthreads();
    for (int e = e0 + tid; e < e1; e += 512) {
        int2 sd = ebuf[e];
        int pos = atomicAdd(&cur[sd.y - n0], 1);
        col[e0 + pos] = sd.x;
    }
    if (b == 0 && tid == 0) rowptr[N_NODES] = N_EDGES;
}

// pad x [N,9] -> x16b [N,16] bf16 (zeros in cols 9..15); one thread per node
__global__ void pad_x_kernel(const float* __restrict__ x, ushort16* __restrict__ x16b) {
    int n = blockIdx.x * 256 + threadIdx.x;
    if (n >= N_NODES) return;
    uint32 w[8];
    #pragma unroll
    for (int p = 0; p < 8; ++p) {
        int k0 = p * 2, k1 = p * 2 + 1;
        uint32 lo = (k0 < F_IN) ? f2bf(x[n * F_IN + k0]) : 0u;
        uint32 hi = (k1 < F_IN) ? f2bf(x[n * F_IN + k1]) : 0u;
        w[p] = lo | (hi << 16);
    }
    uint4* dst = reinterpret_cast<uint4*>(&x16b[(size_t)n * 16]);
    dst[0] = make_uint4(w[0], w[1], w[2], w[3]);
    dst[1] = make_uint4(w[4], w[5], w[6], w[7]);
}

// layer-1 gather on bf16 x16b, pre-scaled by 1/deg: 4 threads/node, 4 feats each
__global__ void agg1_kernel(const ushort16* __restrict__ x16b,
                            const int* __restrict__ rowptr,
                            const int* __restrict__ col,
                            float* __restrict__ s16) {
    int t = blockIdx.x * blockDim.x + threadIdx.x;
    if (t >= N_NODES * 4) return;
    int n = t >> 2, q4 = (t & 3) * 4;
    int lo = rowptr[n], hi = rowptr[n + 1];
    float4 a = make_float4(0.f, 0.f, 0.f, 0.f);
    #pragma unroll 4
    for (int i = lo; i < hi; ++i) {
        int c = col[i];
        uint2 d = *reinterpret_cast<const uint2*>(&x16b[(size_t)c * 16 + q4]);
        a.x += bfl(d.x); a.y += bfh(d.x);
        a.z += bfl(d.y); a.w += bfh(d.y);
    }
    float inv = 1.0f / fmaxf((float)(hi - lo), 1.0f);
    a.x *= inv; a.y *= inv; a.z *= inv; a.w *= inv;
    *reinterpret_cast<float4*>(&s16[(size_t)n * 16 + q4]) = a;
}

// layer-1 dense only: h1 = relu(s16@Wl1 + x@Wr1 + b1)
// -> h1b (bf16, for gather2) and poolH (f32 graph-sum, grouped atomics)
__global__ __launch_bounds__(256) void l1_kernel(const float* __restrict__ x,
                                                 const float* __restrict__ s16,
                                                 const float* __restrict__ Wl1,
                                                 const float* __restrict__ Wr1,
                                                 const float* __restrict__ b1,
                                                 const int* __restrict__ batch,
                                                 ushort16* __restrict__ h1b,
                                                 float* __restrict__ poolH) {
    __shared__ float w1s[F_IN * 128];    // [f][ Wl1 | Wr1 ]
    __shared__ float bs[HID];
    __shared__ float ss[64 * 17];        // pre-scaled agg tile
    __shared__ float xs[64 * 10];        // x tile (f32, exact)
    __shared__ float hs[64 * 65];        // h1 tile (f32, for pool)
    int tid = threadIdx.x;
    int n0 = blockIdx.x * 64;
    for (int i = tid; i < F_IN * HID; i += 256) {
        int f = i >> 6, j = i & 63;
        w1s[f * 128 + j]      = Wl1[i];
        w1s[f * 128 + 64 + j] = Wr1[i];
    }
    if (tid < HID) bs[tid] = b1[tid];
    for (int i = tid; i < 64 * 16; i += 256) {
        int r = i >> 4, f = i & 15;
        int n = n0 + r;
        ss[r * 17 + f] = (n < N_NODES) ? s16[(size_t)n * 16 + f] : 0.0f;
    }
    for (int i = tid; i < 64 * F_IN; i += 256) {
        int r = i / F_IN, f = i - r * F_IN;
        int n = n0 + r;
        xs[r * 10 + f] = (n < N_NODES) ? x[(size_t)n * F_IN + f] : 0.0f;
    }
    __syncthreads();

    int r = tid >> 2, cg = tid & 3, k0 = cg * 16;   // 64 rows x 4 col-groups
    float h[16];
    #pragma unroll
    for (int kk = 0; kk < 16; ++kk) {
        int k = k0 + kk;
        float v = bs[k];
        #pragma unroll
        for (int f = 0; f < F_IN; ++f)
            v += ss[r * 17 + f] * w1s[f * 128 + k]
               + xs[r * 10 + f] * w1s[f * 128 + 64 + k];
        v = fmaxf(v, 0.0f);
        h[kk] = v;
        hs[r * 65 + k] = v;              // 2-way bank alias only (free)
    }
    int n = n0 + r;
    if (n < N_NODES) {
        uint32 w[8];
        #pragma unroll
        for (int p = 0; p < 8; ++p)
            w[p] = (uint32)f2bf(h[2 * p]) | ((uint32)f2bf(h[2 * p + 1]) << 16);
        uint4* dst = reinterpret_cast<uint4*>(&h1b[(size_t)n * HID + k0]);
        dst[0] = make_uint4(w[0], w[1], w[2], w[3]);
        dst[1] = make_uint4(w[4], w[5], w[6], w[7]);
    }
    __syncthreads();
    if (tid < HID) {                     // grouped poolH atomics (batch sorted)
        int j = tid;
        int cur = batch[(n0 < N_NODES) ? n0 : (N_NODES - 1)];
        float v = (n0 < N_NODES) ? hs[0 * 65 + j] : 0.0f;
        for (int rr = 1; rr < 64; ++rr) {
            int nn = n0 + rr;
            bool ok = (nn < N_NODES);
            int g = batch[ok ? nn : (N_NODES - 1)];
            float val = ok ? hs[rr * 65 + j] : 0.0f;
            if (g == cur) v += val;
            else { atomicAdd(&poolH[cur * HID + j], v); cur = g; v = val; }
        }
        atomicAdd(&poolH[cur * HID + j], v);
    }
}

// layer-2 gather on bf16 h1: wave per node; mean-agg -> poolA (grouped atomics)
__global__ __launch_bounds__(1024) void gather2_kernel(const ushort16* __restrict__ h1b,
                                                       const int* __restrict__ rowptr,
                                                       const int* __restrict__ col,
                                                       const int* __restrict__ batch,
                                                       float* __restrict__ poolA) {
    __shared__ float sh[16][HID];
    int w = threadIdx.x >> 6;
    int lane = threadIdx.x & 63;
    int q = lane >> 4;
    int f4 = (lane & 15) * 4;
    int n = blockIdx.x * 16 + w;
    int lo = rowptr[n], hi = rowptr[n + 1];
    float4 acc = make_float4(0.f, 0.f, 0.f, 0.f);
    #pragma unroll 2
    for (int i = lo + q; i < hi; i += 4) {
        int c = col[i];
        uint2 d = *reinterpret_cast<const uint2*>(&h1b[(size_t)c * HID + f4]);
        acc.x += bfl(d.x); acc.y += bfh(d.x);
        acc.z += bfl(d.y); acc.w += bfh(d.y);
    }
    acc.x += __shfl_xor(acc.x, 16, 64);
    acc.y += __shfl_xor(acc.y, 16, 64);
    acc.z += __shfl_xor(acc.z, 16, 64);
    acc.w += __shfl_xor(acc.w, 16, 64);
    acc.x += __shfl_xor(acc.x, 32, 64);
    acc.y += __shfl_xor(acc.y, 32, 64);
    acc.z += __shfl_xor(acc.z, 32, 64);
    acc.w += __shfl_xor(acc.w, 32, 64);
    float inv = 1.0f / fmaxf((float)(hi - lo), 1.0f);
    if (lane < 16) {
        float4 r = make_float4(acc.x * inv, acc.y * inv, acc.z * inv, acc.w * inv);
        *reinterpret_cast<float4*>(&sh[w][f4]) = r;
    }
    __syncthreads();
    if (threadIdx.x < HID) {
        int j = threadIdx.x;
        int base = blockIdx.x * 16;
        int cur = batch[base];
        float v = sh[0][j];
        for (int r = 1; r < 16; ++r) {
            int g = batch[base + r];
            float val = sh[r][j];
            if (g == cur) v += val;
            else { atomicAdd(&poolA[cur * HID + j], v); cur = g; v = val; }
        }
        atomicAdd(&poolA[cur * HID + j], v);
    }
}

// readout: wave per graph. xg = (poolA@Wl2 + poolH@Wr2)/cnt + b2, then MLP.
__global__ void mlp_kernel(const float* __restrict__ poolA,
                           const float* __restrict__ poolH,
                           const int* __restrict__ batch,
                           const float* __restrict__ Wl2,
                           const float* __restrict__ Wr2,
                           const float* __restrict__ b2,
                           const float* __restrict__ Wm1,
                           const float* __restrict__ bm1,
                           const float* __restrict__ Wm2,
                           const float* __restrict__ bm2,
                           float* __restrict__ out) {
    __shared__ float spA[4][HID], spH[4][HID], sx[4][HID];
    int t = blockIdx.x * blockDim.x + threadIdx.x;
    int g = t >> 6;
    int j = t & 63;
    int w = threadIdx.x >> 6;
    if (g >= N_GRAPHS) return;
    int lo = 0, hi = N_NODES;
    while (lo < hi) { int m = (lo + hi) >> 1; if (batch[m] < g) lo = m + 1; else hi = m; }
    int start = lo;
    lo = 0; hi = N_NODES;
    while (lo < hi) { int m = (lo + hi) >> 1; if (batch[m] < g + 1) lo = m + 1; else hi = m; }
    int cntg = lo - start;
    float inv = 1.0f / fmaxf((float)cntg, 1.0f);
    spA[w][j] = poolA[g * HID + j];
    spH[w][j] = poolH[g * HID + j];
    float acc = 0.0f;
    #pragma unroll 8
    for (int k = 0; k < HID; ++k)
        acc += spA[w][k] * Wl2[k * HID + j] + spH[w][k] * Wr2[k * HID + j];
    float xg = acc * inv + b2[j];
    sx[w][j] = xg;
    if (j < 32) {
        float a = bm1[j];
        #pragma unroll 8
        for (int k = 0; k < HID; ++k)
            a += sx[w][k] * Wm1[k * 32 + j];
        float r = fmaxf(a, 0.0f) * Wm2[j];
        #pragma unroll
        for (int off = 16; off > 0; off >>= 1)
            r += __shfl_down(r, off, 32);
        if (j == 0)
            out[g] = 1.0f / (1.0f + expf(-(r + bm2[0])));
    }
}

extern "C" void kernel_launch(void* const* d_in, const int* in_sizes, int n_in,
                              void* d_out, int out_size, void* d_ws, size_t ws_size,
                              hipStream_t stream) {
    const float* x    = (const float*)d_in[0];
    const int*   ei   = (const int*)d_in[1];
    // d_in[2] = edge_attr (all zeros, unused)
    const int*   batch= (const int*)d_in[3];
    const float* Wl1  = (const float*)d_in[4];
    const float* Wr1  = (const float*)d_in[5];
    const float* b1   = (const float*)d_in[6];
    const float* Wl2  = (const float*)d_in[7];
    const float* Wr2  = (const float*)d_in[8];
    const float* b2   = (const float*)d_in[9];
    const float* Wm1  = (const float*)d_in[10];
    const float* bm1  = (const float*)d_in[11];
    const float* Wm2  = (const float*)d_in[12];
    const float* bm2  = (const float*)d_in[13];
    float* out = (float*)d_out;

    int*   wsi = (int*)d_ws;
    float* wsf = (float*)d_ws;
    float*    poolA  = wsf;
    float*    poolH  = wsf + 64000;
    int*      bcnt   = wsi + 128000;
    int*      gcur   = wsi + 128200;
    int*      gbase  = wsi + 128400;
    int*      rowptr = wsi + 128600;
    int*      col    = wsi + 228604;
    int2*     ebuf   = (int2*)(wsi + 1828604);
    ushort16* x16b   = (ushort16*)(wsi + 5028604);
    float*    s16    = wsf + 5828604;
    ushort16* h1b    = (ushort16*)(wsi + 7428604);

    hipMemsetAsync(d_ws, 0, 128200 * sizeof(int), stream);   // poolA+poolH+bcnt

    {   int bl = (N_EDGES + CHUNK - 1) / CHUNK;              // 391
        bhist_kernel<<<bl, 256, 0, stream>>>(ei, bcnt);
    }
    scan_b_kernel<<<1, 256, 0, stream>>>(bcnt, gbase, gcur);
    {   int bl = (N_EDGES + CHUNK - 1) / CHUNK;              // 391
        bscatter_kernel<<<bl, 256, 0, stream>>>(ei, gcur, ebuf);
    }
    build_csr_kernel<<<NBUCK, 512, 0, stream>>>(ebuf, gbase, rowptr, col);
    {   int th = 256, bl = (N_NODES + th - 1) / th;
        pad_x_kernel<<<bl, th, 0, stream>>>(x, x16b);
    }
    {   int th = 256, bl = (N_NODES * 4 + th - 1) / th;
        agg1_kernel<<<bl, th, 0, stream>>>(x16b, rowptr, col, s16);
    }
    {   int th = 256, bl = (N_NODES + 63) / 64;              // 1563
        l1_kernel<<<bl, th, 0, stream>>>(x, s16, Wl1, Wr1, b1, batch, h1b, poolH);
    }
    {   int th = 1024, bl = N_NODES / 16;                    // 6250
        gather2_kernel<<<bl, th, 0, stream>>>(h1b, rowptr, col, batch, poolA);
    }
    {   int th = 256, bl = (N_GRAPHS * 64) / th;             // 250
        mlp_kernel<<<bl, th, 0, stream>>>(poolA, poolH, batch,
                                          Wl2, Wr2, b2, Wm1, bm1, Wm2, bm2, out);
    }
}

// Round 8
// 161.754 us; speedup vs baseline: 3.1261x; 1.1473x over previous
//
#include <hip/hip_runtime.h>
#include <math.h>

#define N_NODES  100000
#define N_EDGES  1600000
#define N_GRAPHS 1000
#define F_IN     9
#define HID      64
#define NBUCK    196    // ceil(N_NODES / 512), bucket = dst >> 9
#define BCAP     12288  // fixed capacity per bucket (mean 8163, +45 sigma)
#define CHUNK    4096   // edges per partition block

typedef unsigned int   uint32;
typedef unsigned short ushort16;

// ---------------------------------------------------------------------------
// Workspace layout (4-byte words):
//   [0,        64000)     poolA  (float) -- zeroed (graph-sum of mean-agg(h1))
//   [64000,    128000)    poolH  (float) -- zeroed (graph-sum of h1)
//   [128000,   128196)    gcur   (int)   -- zeroed (bucket fill cursors)
//   ZERO region = [0, 128200)
//   [128200,   328200)    rowcnt (int2 per node: {col start, degree})
//   [328204,   2736652)   col    (int, NBUCK*BCAP)
//   [2736652,  7553548)   ebuf   (int2, NBUCK*BCAP)
//   [7553548,  8353548)   x16b   (bf16, N*16)
//   [8353548,  11553548)  h1b    (bf16, N*64)
// Total 11.55M words = 46.2 MB.
// ---------------------------------------------------------------------------

__device__ __forceinline__ float bfl(uint32 w) { return __uint_as_float(w << 16); }
__device__ __forceinline__ float bfh(uint32 w) { return __uint_as_float(w & 0xffff0000u); }
__device__ __forceinline__ ushort16 f2bf(float f) {
    uint32 u = __float_as_uint(f);
    u += 0x7fffu + ((u >> 16) & 1u);           // round-to-nearest-even
    return (ushort16)(u >> 16);
}

// K1: pad x -> x16b (bf16) AND fixed-capacity bucket partition of edges
__global__ __launch_bounds__(256) void pad_part_kernel(const float* __restrict__ x,
                                                       const int* __restrict__ ei,
                                                       int* __restrict__ gcur,
                                                       int2* __restrict__ ebuf,
                                                       ushort16* __restrict__ x16b) {
    __shared__ int lcnt[NBUCK], lbase[NBUCK];
    int tid = threadIdx.x;

    // --- pad phase: one node per thread (391*256 = 100096 >= N) ---
    int n = blockIdx.x * 256 + tid;
    if (n < N_NODES) {
        uint32 w[8];
        #pragma unroll
        for (int p = 0; p < 8; ++p) {
            int k0 = p * 2, k1 = p * 2 + 1;
            uint32 lo = (k0 < F_IN) ? f2bf(x[(size_t)n * F_IN + k0]) : 0u;
            uint32 hi = (k1 < F_IN) ? f2bf(x[(size_t)n * F_IN + k1]) : 0u;
            w[p] = lo | (hi << 16);
        }
        uint4* dst = reinterpret_cast<uint4*>(&x16b[(size_t)n * 16]);
        dst[0] = make_uint4(w[0], w[1], w[2], w[3]);
        dst[1] = make_uint4(w[4], w[5], w[6], w[7]);
    }

    // --- partition phase: block-aggregated reservation into fixed buckets ---
    for (int i = tid; i < NBUCK; i += 256) lcnt[i] = 0;
    __syncthreads();
    int e0 = blockIdx.x * CHUNK;
    int e1 = e0 + CHUNK; if (e1 > N_EDGES) e1 = N_EDGES;
    for (int e = e0 + tid; e < e1; e += 256)
        atomicAdd(&lcnt[ei[N_EDGES + e] >> 9], 1);
    __syncthreads();
    for (int i = tid; i < NBUCK; i += 256)
        lbase[i] = atomicAdd(&gcur[i], lcnt[i]);
    __syncthreads();
    for (int i = tid; i < NBUCK; i += 256) lcnt[i] = 0;
    __syncthreads();
    for (int e = e0 + tid; e < e1; e += 256) {
        int src = ei[e];
        int dst = ei[N_EDGES + e];
        int b = dst >> 9;
        int pos = lbase[b] + atomicAdd(&lcnt[b], 1);
        if (pos < BCAP)
            ebuf[(size_t)b * BCAP + pos] = make_int2(src, dst);
    }
}

// K2: per-bucket CSR build (512 nodes/bucket), LDS count+scan+place
__global__ __launch_bounds__(512) void build_csr_kernel(const int2* __restrict__ ebuf,
                                                        const int* __restrict__ gcur,
                                                        int2* __restrict__ rowcnt,
                                                        int* __restrict__ col) {
    __shared__ int cnt[512];
    __shared__ int cur[512];
    __shared__ int wsum[8];
    int b = blockIdx.x;
    int n0 = b << 9;
    int tid = threadIdx.x;
    int ec = gcur[b]; if (ec > BCAP) ec = BCAP;
    size_t base = (size_t)b * BCAP;
    cnt[tid] = 0;
    __syncthreads();
    for (int e = tid; e < ec; e += 512)
        atomicAdd(&cnt[ebuf[base + e].y - n0], 1);
    __syncthreads();
    int v = cnt[tid];
    int lane = tid & 63, wid = tid >> 6;
    int s = v;
    #pragma unroll
    for (int off = 1; off < 64; off <<= 1) {
        int u = __shfl_up(s, off, 64);
        if (lane >= off) s += u;
    }
    if (lane == 63) wsum[wid] = s;
    __syncthreads();
    int add = 0;
    for (int w = 0; w < wid; ++w) add += wsum[w];
    int off_ex = s - v + add;            // exclusive scan within bucket
    int n = n0 + tid;
    if (n < N_NODES) rowcnt[n] = make_int2((int)base + off_ex, v);
    cur[tid] = off_ex;
    __syncthreads();
    for (int e = tid; e < ec; e += 512) {
        int2 sd = ebuf[base + e];
        int pos = atomicAdd(&cur[sd.y - n0], 1);
        col[base + pos] = sd.x;
    }
}

// K3: fused layer-1 aggregation (gather) + dense + poolH atomics. 64 nodes/block.
__global__ __launch_bounds__(256) void agg_l1_kernel(const float* __restrict__ x,
                                                     const ushort16* __restrict__ x16b,
                                                     const int2* __restrict__ rowcnt,
                                                     const int* __restrict__ col,
                                                     const float* __restrict__ Wl1,
                                                     const float* __restrict__ Wr1,
                                                     const float* __restrict__ b1,
                                                     const int* __restrict__ batch,
                                                     ushort16* __restrict__ h1b,
                                                     float* __restrict__ poolH) {
    __shared__ float w1s[F_IN * 128];    // [f][ Wl1 | Wr1 ]
    __shared__ float bs[HID];
    __shared__ float ss[64 * 17];        // mean-agg tile (f32)
    __shared__ float xs[64 * 10];        // x tile (f32, exact)
    __shared__ float hs[64 * 65];        // h1 tile (f32, for pool)
    int tid = threadIdx.x;
    int n0 = blockIdx.x * 64;
    for (int i = tid; i < F_IN * HID; i += 256) {
        int f = i >> 6, j = i & 63;
        w1s[f * 128 + j]      = Wl1[i];
        w1s[f * 128 + 64 + j] = Wr1[i];
    }
    if (tid < HID) bs[tid] = b1[tid];
    for (int i = tid; i < 64 * F_IN; i += 256) {
        int r = i / F_IN, f = i - r * F_IN;
        int n = n0 + r;
        xs[r * 10 + f] = (n < N_NODES) ? x[(size_t)n * F_IN + f] : 0.0f;
    }

    // gather phase: 4 threads per node, 4 features (uint2) each
    {
        int r = tid >> 2, q4 = (tid & 3) * 4;
        int n = n0 + r;
        float4 a = make_float4(0.f, 0.f, 0.f, 0.f);
        if (n < N_NODES) {
            int2 rc = rowcnt[n];
            #pragma unroll 4
            for (int i = 0; i < rc.y; ++i) {
                int c = col[rc.x + i];
                uint2 d = *reinterpret_cast<const uint2*>(&x16b[(size_t)c * 16 + q4]);
                a.x += bfl(d.x); a.y += bfh(d.x);
                a.z += bfl(d.y); a.w += bfh(d.y);
            }
            float inv = 1.0f / fmaxf((float)rc.y, 1.0f);
            a.x *= inv; a.y *= inv; a.z *= inv; a.w *= inv;
        }
        ss[r * 17 + q4 + 0] = a.x;
        ss[r * 17 + q4 + 1] = a.y;
        ss[r * 17 + q4 + 2] = a.z;
        ss[r * 17 + q4 + 3] = a.w;
    }
    __syncthreads();

    // dense phase: h1 = relu(agg@Wl1 + x@Wr1 + b1); 64 rows x 4 col-groups
    int r = tid >> 2, cg = tid & 3, k0 = cg * 16;
    float h[16];
    #pragma unroll
    for (int kk = 0; kk < 16; ++kk) {
        int k = k0 + kk;
        float v = bs[k];
        #pragma unroll
        for (int f = 0; f < F_IN; ++f)
            v += ss[r * 17 + f] * w1s[f * 128 + k]
               + xs[r * 10 + f] * w1s[f * 128 + 64 + k];
        v = fmaxf(v, 0.0f);
        h[kk] = v;
        hs[r * 65 + k] = v;
    }
    int n = n0 + r;
    if (n < N_NODES) {
        uint32 w[8];
        #pragma unroll
        for (int p = 0; p < 8; ++p)
            w[p] = (uint32)f2bf(h[2 * p]) | ((uint32)f2bf(h[2 * p + 1]) << 16);
        uint4* dst = reinterpret_cast<uint4*>(&h1b[(size_t)n * HID + k0]);
        dst[0] = make_uint4(w[0], w[1], w[2], w[3]);
        dst[1] = make_uint4(w[4], w[5], w[6], w[7]);
    }
    __syncthreads();
    if (tid < HID) {                     // grouped poolH atomics (batch sorted)
        int j = tid;
        int cur = batch[(n0 < N_NODES) ? n0 : (N_NODES - 1)];
        float v = (n0 < N_NODES) ? hs[0 * 65 + j] : 0.0f;
        for (int rr = 1; rr < 64; ++rr) {
            int nn = n0 + rr;
            bool ok = (nn < N_NODES);
            int g = batch[ok ? nn : (N_NODES - 1)];
            float val = ok ? hs[rr * 65 + j] : 0.0f;
            if (g == cur) v += val;
            else { atomicAdd(&poolH[cur * HID + j], v); cur = g; v = val; }
        }
        atomicAdd(&poolH[cur * HID + j], v);
    }
}

// K4: layer-2 gather on bf16 h1, uint4-wide: wave/node, 8 edge-slots x 8 lane-groups
__global__ __launch_bounds__(1024) void gather2_kernel(const ushort16* __restrict__ h1b,
                                                       const int2* __restrict__ rowcnt,
                                                       const int* __restrict__ col,
                                                       const int* __restrict__ batch,
                                                       float* __restrict__ poolA) {
    __shared__ float sh[16][HID];
    int w = threadIdx.x >> 6;
    int lane = threadIdx.x & 63;
    int slot = lane >> 3;                // 8 edge slots
    int grp  = lane & 7;                 // 8 feature groups x 8 bf16
    int n = blockIdx.x * 16 + w;
    int2 rc = rowcnt[n];
    float a[8];
    #pragma unroll
    for (int k = 0; k < 8; ++k) a[k] = 0.0f;
    #pragma unroll 2
    for (int i = slot; i < rc.y; i += 8) {
        int c = col[rc.x + i];
        uint4 d = *reinterpret_cast<const uint4*>(&h1b[(size_t)c * HID + grp * 8]);
        a[0] += bfl(d.x); a[1] += bfh(d.x);
        a[2] += bfl(d.y); a[3] += bfh(d.y);
        a[4] += bfl(d.z); a[5] += bfh(d.z);
        a[6] += bfl(d.w); a[7] += bfh(d.w);
    }
    #pragma unroll
    for (int k = 0; k < 8; ++k) {
        a[k] += __shfl_xor(a[k], 8, 64);
        a[k] += __shfl_xor(a[k], 16, 64);
        a[k] += __shfl_xor(a[k], 32, 64);
    }
    float inv = 1.0f / fmaxf((float)rc.y, 1.0f);
    if (slot == 0) {
        #pragma unroll
        for (int k = 0; k < 8; ++k)
            sh[w][grp * 8 + k] = a[k] * inv;
    }
    __syncthreads();
    if (threadIdx.x < HID) {             // grouped poolA atomics (batch sorted)
        int j = threadIdx.x;
        int base = blockIdx.x * 16;
        int cur = batch[base];
        float v = sh[0][j];
        for (int r = 1; r < 16; ++r) {
            int g = batch[base + r];
            float val = sh[r][j];
            if (g == cur) v += val;
            else { atomicAdd(&poolA[cur * HID + j], v); cur = g; v = val; }
        }
        atomicAdd(&poolA[cur * HID + j], v);
    }
}

// K5: readout. xg = (poolA@Wl2 + poolH@Wr2)/cnt + b2, then 64->32->1 MLP.
__global__ void mlp_kernel(const float* __restrict__ poolA,
                           const float* __restrict__ poolH,
                           const int* __restrict__ batch,
                           const float* __restrict__ Wl2,
                           const float* __restrict__ Wr2,
                           const float* __restrict__ b2,
                           const float* __restrict__ Wm1,
                           const float* __restrict__ bm1,
                           const float* __restrict__ Wm2,
                           const float* __restrict__ bm2,
                           float* __restrict__ out) {
    __shared__ float spA[4][HID], spH[4][HID], sx[4][HID];
    int t = blockIdx.x * blockDim.x + threadIdx.x;
    int g = t >> 6;
    int j = t & 63;
    int w = threadIdx.x >> 6;
    if (g >= N_GRAPHS) return;
    int lo = 0, hi = N_NODES;
    while (lo < hi) { int m = (lo + hi) >> 1; if (batch[m] < g) lo = m + 1; else hi = m; }
    int start = lo;
    lo = 0; hi = N_NODES;
    while (lo < hi) { int m = (lo + hi) >> 1; if (batch[m] < g + 1) lo = m + 1; else hi = m; }
    int cntg = lo - start;
    float inv = 1.0f / fmaxf((float)cntg, 1.0f);
    spA[w][j] = poolA[g * HID + j];
    spH[w][j] = poolH[g * HID + j];
    float acc = 0.0f;
    #pragma unroll 8
    for (int k = 0; k < HID; ++k)
        acc += spA[w][k] * Wl2[k * HID + j] + spH[w][k] * Wr2[k * HID + j];
    sx[w][j] = acc * inv + b2[j];
    if (j < 32) {
        float a = bm1[j];
        #pragma unroll 8
        for (int k = 0; k < HID; ++k)
            a += sx[w][k] * Wm1[k * 32 + j];
        float r = fmaxf(a, 0.0f) * Wm2[j];
        #pragma unroll
        for (int off = 16; off > 0; off >>= 1)
            r += __shfl_down(r, off, 32);
        if (j == 0)
            out[g] = 1.0f / (1.0f + expf(-(r + bm2[0])));
    }
}

extern "C" void kernel_launch(void* const* d_in, const int* in_sizes, int n_in,
                              void* d_out, int out_size, void* d_ws, size_t ws_size,
                              hipStream_t stream) {
    const float* x    = (const float*)d_in[0];
    const int*   ei   = (const int*)d_in[1];
    // d_in[2] = edge_attr (all zeros, unused)
    const int*   batch= (const int*)d_in[3];
    const float* Wl1  = (const float*)d_in[4];
    const float* Wr1  = (const float*)d_in[5];
    const float* b1   = (const float*)d_in[6];
    const float* Wl2  = (const float*)d_in[7];
    const float* Wr2  = (const float*)d_in[8];
    const float* b2   = (const float*)d_in[9];
    const float* Wm1  = (const float*)d_in[10];
    const float* bm1  = (const float*)d_in[11];
    const float* Wm2  = (const float*)d_in[12];
    const float* bm2  = (const float*)d_in[13];
    float* out = (float*)d_out;

    int*   wsi = (int*)d_ws;
    float* wsf = (float*)d_ws;
    float*    poolA  = wsf;
    float*    poolH  = wsf + 64000;
    int*      gcur   = wsi + 128000;
    int2*     rowcnt = (int2*)(wsi + 128200);
    int*      col    = wsi + 328204;
    int2*     ebuf   = (int2*)(wsi + 2736652);
    ushort16* x16b   = (ushort16*)(wsi + 7553548);
    ushort16* h1b    = (ushort16*)(wsi + 8353548);

    hipMemsetAsync(d_ws, 0, 128200 * sizeof(int), stream);   // poolA+poolH+gcur

    {   int bl = (N_EDGES + CHUNK - 1) / CHUNK;              // 391
        pad_part_kernel<<<bl, 256, 0, stream>>>(x, ei, gcur, ebuf, x16b);
    }
    build_csr_kernel<<<NBUCK, 512, 0, stream>>>(ebuf, gcur, rowcnt, col);
    {   int th = 256, bl = (N_NODES + 63) / 64;              // 1563
        agg_l1_kernel<<<bl, th, 0, stream>>>(x, x16b, rowcnt, col, Wl1, Wr1, b1,
                                             batch, h1b, poolH);
    }
    {   int th = 1024, bl = N_NODES / 16;                    // 6250
        gather2_kernel<<<bl, th, 0, stream>>>(h1b, rowcnt, col, batch, poolA);
    }
    {   int th = 256, bl = (N_GRAPHS * 64) / th;             // 250
        mlp_kernel<<<bl, th, 0, stream>>>(poolA, poolH, batch,
                                          Wl2, Wr2, b2, Wm1, bm1, Wm2, bm2, out);
    }
}

// Round 9
// 154.120 us; speedup vs baseline: 3.2810x; 1.0495x over previous
//
#include <hip/hip_runtime.h>
#include <math.h>

#define N_NODES  100000
#define N_EDGES  1600000
#define N_GRAPHS 1000
#define F_IN     9
#define HID      64
#define NBUCK    196    // ceil(N_NODES / 512), bucket = dst >> 9
#define BCAP     12288  // fixed capacity per bucket (mean 8163, +45 sigma)
#define CHUNK    4096   // edges per partition block

typedef unsigned int uint32;
typedef float v2f __attribute__((ext_vector_type(2)));

// ---------------------------------------------------------------------------
// Workspace layout (4-byte words):
//   [0,        64000)     poolA  (float) -- zeroed (graph-sum of mean-agg(h1))
//   [64000,    128000)    poolH  (float) -- zeroed (graph-sum of h1)
//   [128000,   128196)    gcur   (int)   -- zeroed (bucket fill cursors)
//   ZERO region = [0, 128200)
//   [128200,   328200)    rowcnt (int2 per node: {col start, degree})
//   [328204,   2736652)   col    (int, NBUCK*BCAP)
//   [2736652,  7553548)   ebuf   (int2, NBUCK*BCAP)
//   [7553548,  7953548)   x8b    (fp8 e4m3, N*16 = 16 B/node, 4 words/node)
//   [7953548,  9553548)   h1b    (fp8 e4m3, N*64 = 64 B/node, 16 words/node)
// Total 9.55M words = 38.2 MB.
// ---------------------------------------------------------------------------

// HW fp8 e4m3 converters (gfx950 OCP e4m3fn; roundtrip-consistent)
__device__ __forceinline__ uint32 pk_lo(float a, float b, uint32 old) {
    return (uint32)__builtin_amdgcn_cvt_pk_fp8_f32(a, b, (int)old, false);
}
__device__ __forceinline__ uint32 pk_hi(float a, float b, uint32 old) {
    return (uint32)__builtin_amdgcn_cvt_pk_fp8_f32(a, b, (int)old, true);
}

// K1: pad/encode x -> x8b (fp8) AND fixed-capacity bucket partition of edges
__global__ __launch_bounds__(256) void pad_part_kernel(const float* __restrict__ x,
                                                       const int* __restrict__ ei,
                                                       int* __restrict__ gcur,
                                                       int2* __restrict__ ebuf,
                                                       uint32* __restrict__ x8b) {
    __shared__ int lcnt[NBUCK], lbase[NBUCK];
    int tid = threadIdx.x;

    // --- encode phase: one node per thread (391*256 = 100096 >= N) ---
    int n = blockIdx.x * 256 + tid;
    if (n < N_NODES) {
        uint32 w[4];
        #pragma unroll
        for (int p = 0; p < 4; ++p) {
            float v0 = (4 * p + 0 < F_IN) ? x[(size_t)n * F_IN + 4 * p + 0] : 0.0f;
            float v1 = (4 * p + 1 < F_IN) ? x[(size_t)n * F_IN + 4 * p + 1] : 0.0f;
            float v2 = (4 * p + 2 < F_IN) ? x[(size_t)n * F_IN + 4 * p + 2] : 0.0f;
            float v3 = (4 * p + 3 < F_IN) ? x[(size_t)n * F_IN + 4 * p + 3] : 0.0f;
            w[p] = pk_hi(v2, v3, pk_lo(v0, v1, 0u));
        }
        *reinterpret_cast<uint4*>(&x8b[(size_t)n * 4]) =
            make_uint4(w[0], w[1], w[2], w[3]);
    }

    // --- partition phase: block-aggregated reservation into fixed buckets ---
    for (int i = tid; i < NBUCK; i += 256) lcnt[i] = 0;
    __syncthreads();
    int e0 = blockIdx.x * CHUNK;
    int e1 = e0 + CHUNK; if (e1 > N_EDGES) e1 = N_EDGES;
    for (int e = e0 + tid; e < e1; e += 256)
        atomicAdd(&lcnt[ei[N_EDGES + e] >> 9], 1);
    __syncthreads();
    for (int i = tid; i < NBUCK; i += 256)
        lbase[i] = atomicAdd(&gcur[i], lcnt[i]);
    __syncthreads();
    for (int i = tid; i < NBUCK; i += 256) lcnt[i] = 0;
    __syncthreads();
    for (int e = e0 + tid; e < e1; e += 256) {
        int src = ei[e];
        int dst = ei[N_EDGES + e];
        int b = dst >> 9;
        int pos = lbase[b] + atomicAdd(&lcnt[b], 1);
        if (pos < BCAP)
            ebuf[(size_t)b * BCAP + pos] = make_int2(src, dst);
    }
}

// K2: per-bucket CSR build (512 nodes/bucket), LDS count+scan+place
__global__ __launch_bounds__(512) void build_csr_kernel(const int2* __restrict__ ebuf,
                                                        const int* __restrict__ gcur,
                                                        int2* __restrict__ rowcnt,
                                                        int* __restrict__ col) {
    __shared__ int cnt[512];
    __shared__ int cur[512];
    __shared__ int wsum[8];
    int b = blockIdx.x;
    int n0 = b << 9;
    int tid = threadIdx.x;
    int ec = gcur[b]; if (ec > BCAP) ec = BCAP;
    size_t base = (size_t)b * BCAP;
    cnt[tid] = 0;
    __syncthreads();
    for (int e = tid; e < ec; e += 512)
        atomicAdd(&cnt[ebuf[base + e].y - n0], 1);
    __syncthreads();
    int v = cnt[tid];
    int lane = tid & 63, wid = tid >> 6;
    int s = v;
    #pragma unroll
    for (int off = 1; off < 64; off <<= 1) {
        int u = __shfl_up(s, off, 64);
        if (lane >= off) s += u;
    }
    if (lane == 63) wsum[wid] = s;
    __syncthreads();
    int add = 0;
    for (int w = 0; w < wid; ++w) add += wsum[w];
    int off_ex = s - v + add;            // exclusive scan within bucket
    int n = n0 + tid;
    if (n < N_NODES) rowcnt[n] = make_int2((int)base + off_ex, v);
    cur[tid] = off_ex;
    __syncthreads();
    for (int e = tid; e < ec; e += 512) {
        int2 sd = ebuf[base + e];
        int pos = atomicAdd(&cur[sd.y - n0], 1);
        col[base + pos] = sd.x;
    }
}

// K3: fused layer-1 aggregation (fp8 gather) + dense + poolH atomics. 64 nodes/block.
__global__ __launch_bounds__(256) void agg_l1_kernel(const float* __restrict__ x,
                                                     const uint32* __restrict__ x8b,
                                                     const int2* __restrict__ rowcnt,
                                                     const int* __restrict__ col,
                                                     const float* __restrict__ Wl1,
                                                     const float* __restrict__ Wr1,
                                                     const float* __restrict__ b1,
                                                     const int* __restrict__ batch,
                                                     uint32* __restrict__ h1b,
                                                     float* __restrict__ poolH) {
    __shared__ float w1s[F_IN * 128];    // [f][ Wl1 | Wr1 ]
    __shared__ float bs[HID];
    __shared__ float ss[64 * 17];        // mean-agg tile (f32)
    __shared__ float xs[64 * 10];        // x tile (f32, exact)
    __shared__ float hs[64 * 65];        // h1 tile (f32, for pool)
    int tid = threadIdx.x;
    int n0 = blockIdx.x * 64;
    for (int i = tid; i < F_IN * HID; i += 256) {
        int f = i >> 6, j = i & 63;
        w1s[f * 128 + j]      = Wl1[i];
        w1s[f * 128 + 64 + j] = Wr1[i];
    }
    if (tid < HID) bs[tid] = b1[tid];
    for (int i = tid; i < 64 * F_IN; i += 256) {
        int r = i / F_IN, f = i - r * F_IN;
        int n = n0 + r;
        xs[r * 10 + f] = (n < N_NODES) ? x[(size_t)n * F_IN + f] : 0.0f;
    }

    // gather phase: 4 threads per node, 4 features (one dword fp8x4) each
    {
        int r = tid >> 2, q = tid & 3;
        int n = n0 + r;
        float4 a = make_float4(0.f, 0.f, 0.f, 0.f);
        if (n < N_NODES) {
            int2 rc = rowcnt[n];
            #pragma unroll 4
            for (int i = 0; i < rc.y; ++i) {
                int c = col[rc.x + i];
                uint32 d = x8b[(size_t)c * 4 + q];
                v2f f0 = __builtin_amdgcn_cvt_pk_f32_fp8((int)d, false);
                v2f f1 = __builtin_amdgcn_cvt_pk_f32_fp8((int)d, true);
                a.x += f0[0]; a.y += f0[1];
                a.z += f1[0]; a.w += f1[1];
            }
            float inv = 1.0f / fmaxf((float)rc.y, 1.0f);
            a.x *= inv; a.y *= inv; a.z *= inv; a.w *= inv;
        }
        int q4 = q * 4;
        ss[r * 17 + q4 + 0] = a.x;
        ss[r * 17 + q4 + 1] = a.y;
        ss[r * 17 + q4 + 2] = a.z;
        ss[r * 17 + q4 + 3] = a.w;
    }
    __syncthreads();

    // dense phase: h1 = relu(agg@Wl1 + x@Wr1 + b1); 64 rows x 4 col-groups
    int r = tid >> 2, cg = tid & 3, k0 = cg * 16;
    float h[16];
    #pragma unroll
    for (int kk = 0; kk < 16; ++kk) {
        int k = k0 + kk;
        float v = bs[k];
        #pragma unroll
        for (int f = 0; f < F_IN; ++f)
            v += ss[r * 17 + f] * w1s[f * 128 + k]
               + xs[r * 10 + f] * w1s[f * 128 + 64 + k];
        v = fmaxf(v, 0.0f);
        h[kk] = v;
        hs[r * 65 + k] = v;
    }
    int n = n0 + r;
    if (n < N_NODES) {                   // encode 16 feats -> 4 fp8 words
        uint32 w[4];
        #pragma unroll
        for (int p = 0; p < 4; ++p)
            w[p] = pk_hi(h[4 * p + 2], h[4 * p + 3],
                         pk_lo(h[4 * p + 0], h[4 * p + 1], 0u));
        *reinterpret_cast<uint4*>(&h1b[(size_t)n * 16 + cg * 4]) =
            make_uint4(w[0], w[1], w[2], w[3]);
    }
    __syncthreads();
    if (tid < HID) {                     // grouped poolH atomics (batch sorted)
        int j = tid;
        int cur = batch[(n0 < N_NODES) ? n0 : (N_NODES - 1)];
        float v = (n0 < N_NODES) ? hs[0 * 65 + j] : 0.0f;
        for (int rr = 1; rr < 64; ++rr) {
            int nn = n0 + rr;
            bool ok = (nn < N_NODES);
            int g = batch[ok ? nn : (N_NODES - 1)];
            float val = ok ? hs[rr * 65 + j] : 0.0f;
            if (g == cur) v += val;
            else { atomicAdd(&poolH[cur * HID + j], v); cur = g; v = val; }
        }
        atomicAdd(&poolH[cur * HID + j], v);
    }
}

// K4: layer-2 gather on fp8 h1: wave/node, 8 edge-slots x 8 feature-groups
__global__ __launch_bounds__(1024) void gather2_kernel(const uint32* __restrict__ h1b,
                                                       const int2* __restrict__ rowcnt,
                                                       const int* __restrict__ col,
                                                       const int* __restrict__ batch,
                                                       float* __restrict__ poolA) {
    __shared__ float sh[16][HID];
    int w = threadIdx.x >> 6;
    int lane = threadIdx.x & 63;
    int slot = lane >> 3;                // 8 edge slots
    int grp  = lane & 7;                 // 8 feature groups x 8 fp8
    int n = blockIdx.x * 16 + w;
    int2 rc = rowcnt[n];
    float a[8];
    #pragma unroll
    for (int k = 0; k < 8; ++k) a[k] = 0.0f;
    #pragma unroll 2
    for (int i = slot; i < rc.y; i += 8) {
        int c = col[rc.x + i];
        uint2 d = *reinterpret_cast<const uint2*>(&h1b[(size_t)c * 16 + grp * 2]);
        v2f f0 = __builtin_amdgcn_cvt_pk_f32_fp8((int)d.x, false);
        v2f f1 = __builtin_amdgcn_cvt_pk_f32_fp8((int)d.x, true);
        v2f f2 = __builtin_amdgcn_cvt_pk_f32_fp8((int)d.y, false);
        v2f f3 = __builtin_amdgcn_cvt_pk_f32_fp8((int)d.y, true);
        a[0] += f0[0]; a[1] += f0[1];
        a[2] += f1[0]; a[3] += f1[1];
        a[4] += f2[0]; a[5] += f2[1];
        a[6] += f3[0]; a[7] += f3[1];
    }
    #pragma unroll
    for (int k = 0; k < 8; ++k) {
        a[k] += __shfl_xor(a[k], 8, 64);
        a[k] += __shfl_xor(a[k], 16, 64);
        a[k] += __shfl_xor(a[k], 32, 64);
    }
    float inv = 1.0f / fmaxf((float)rc.y, 1.0f);
    if (slot == 0) {
        #pragma unroll
        for (int k = 0; k < 8; ++k)
            sh[w][grp * 8 + k] = a[k] * inv;
    }
    __syncthreads();
    if (threadIdx.x < HID) {             // grouped poolA atomics (batch sorted)
        int j = threadIdx.x;
        int base = blockIdx.x * 16;
        int cur = batch[base];
        float v = sh[0][j];
        for (int r = 1; r < 16; ++r) {
            int g = batch[base + r];
            float val = sh[r][j];
            if (g == cur) v += val;
            else { atomicAdd(&poolA[cur * HID + j], v); cur = g; v = val; }
        }
        atomicAdd(&poolA[cur * HID + j], v);
    }
}

// K5: readout. xg = (poolA@Wl2 + poolH@Wr2)/cnt + b2, then 64->32->1 MLP.
__global__ void mlp_kernel(const float* __restrict__ poolA,
                           const float* __restrict__ poolH,
                           const int* __restrict__ batch,
                           const float* __restrict__ Wl2,
                           const float* __restrict__ Wr2,
                           const float* __restrict__ b2,
                           const float* __restrict__ Wm1,
                           const float* __restrict__ bm1,
                           const float* __restrict__ Wm2,
                           const float* __restrict__ bm2,
                           float* __restrict__ out) {
    __shared__ float spA[4][HID], spH[4][HID], sx[4][HID];
    int t = blockIdx.x * blockDim.x + threadIdx.x;
    int g = t >> 6;
    int j = t & 63;
    int w = threadIdx.x >> 6;
    if (g >= N_GRAPHS) return;
    int lo = 0, hi = N_NODES;
    while (lo < hi) { int m = (lo + hi) >> 1; if (batch[m] < g) lo = m + 1; else hi = m; }
    int start = lo;
    lo = 0; hi = N_NODES;
    while (lo < hi) { int m = (lo + hi) >> 1; if (batch[m] < g + 1) lo = m + 1; else hi = m; }
    int cntg = lo - start;
    float inv = 1.0f / fmaxf((float)cntg, 1.0f);
    spA[w][j] = poolA[g * HID + j];
    spH[w][j] = poolH[g * HID + j];
    float acc = 0.0f;
    #pragma unroll 8
    for (int k = 0; k < HID; ++k)
        acc += spA[w][k] * Wl2[k * HID + j] + spH[w][k] * Wr2[k * HID + j];
    sx[w][j] = acc * inv + b2[j];
    if (j < 32) {
        float a = bm1[j];
        #pragma unroll 8
        for (int k = 0; k < HID; ++k)
            a += sx[w][k] * Wm1[k * 32 + j];
        float r = fmaxf(a, 0.0f) * Wm2[j];
        #pragma unroll
        for (int off = 16; off > 0; off >>= 1)
            r += __shfl_down(r, off, 32);
        if (j == 0)
            out[g] = 1.0f / (1.0f + expf(-(r + bm2[0])));
    }
}

extern "C" void kernel_launch(void* const* d_in, const int* in_sizes, int n_in,
                              void* d_out, int out_size, void* d_ws, size_t ws_size,
                              hipStream_t stream) {
    const float* x    = (const float*)d_in[0];
    const int*   ei   = (const int*)d_in[1];
    // d_in[2] = edge_attr (all zeros, unused)
    const int*   batch= (const int*)d_in[3];
    const float* Wl1  = (const float*)d_in[4];
    const float* Wr1  = (const float*)d_in[5];
    const float* b1   = (const float*)d_in[6];
    const float* Wl2  = (const float*)d_in[7];
    const float* Wr2  = (const float*)d_in[8];
    const float* b2   = (const float*)d_in[9];
    const float* Wm1  = (const float*)d_in[10];
    const float* bm1  = (const float*)d_in[11];
    const float* Wm2  = (const float*)d_in[12];
    const float* bm2  = (const float*)d_in[13];
    float* out = (float*)d_out;

    int*   wsi = (int*)d_ws;
    float* wsf = (float*)d_ws;
    float*  poolA  = wsf;
    float*  poolH  = wsf + 64000;
    int*    gcur   = wsi + 128000;
    int2*   rowcnt = (int2*)(wsi + 128200);
    int*    col    = wsi + 328204;
    int2*   ebuf   = (int2*)(wsi + 2736652);
    uint32* x8b    = (uint32*)(wsi + 7553548);
    uint32* h1b    = (uint32*)(wsi + 7953548);

    hipMemsetAsync(d_ws, 0, 128200 * sizeof(int), stream);   // poolA+poolH+gcur

    {   int bl = (N_EDGES + CHUNK - 1) / CHUNK;              // 391
        pad_part_kernel<<<bl, 256, 0, stream>>>(x, ei, gcur, ebuf, x8b);
    }
    build_csr_kernel<<<NBUCK, 512, 0, stream>>>(ebuf, gcur, rowcnt, col);
    {   int th = 256, bl = (N_NODES + 63) / 64;              // 1563
        agg_l1_kernel<<<bl, th, 0, stream>>>(x, x8b, rowcnt, col, Wl1, Wr1, b1,
                                             batch, h1b, poolH);
    }
    {   int th = 1024, bl = N_NODES / 16;                    // 6250
        gather2_kernel<<<bl, th, 0, stream>>>(h1b, rowcnt, col, batch, poolA);
    }
    {   int th = 256, bl = (N_GRAPHS * 64) / th;             // 250
        mlp_kernel<<<bl, th, 0, stream>>>(poolA, poolH, batch,
                                          Wl2, Wr2, b2, Wm1, bm1, Wm2, bm2, out);
    }
}